// Round 2
// baseline (275.091 us; speedup 1.0000x reference)
//
#include <hip/hip_runtime.h>
#include <hip/hip_bf16.h>
#include <stdint.h>

#define AS1 __attribute__((address_space(1)))
#define AS3 __attribute__((address_space(3)))

typedef __bf16 bf16x8 __attribute__((ext_vector_type(8)));
typedef float f32x4 __attribute__((ext_vector_type(4)));

__device__ __forceinline__ float fast_tanh(float x) {
    float e = __expf(2.0f * x);           // inf/0 endpoints give +/-1 exactly, no NaN
    return 1.0f - 2.0f / (e + 1.0f);
}

__device__ __forceinline__ float ldin(const void* p, int idx, int f32) {
    return f32 ? ((const float*)p)[idx]
               : __bfloat162float(((const __hip_bfloat16*)p)[idx]);
}

__device__ __forceinline__ void gload_lds16(const __hip_bfloat16* g, AS3 char* l) {
    __builtin_amdgcn_global_load_lds((AS1 void*)g, (AS3 void*)l, 16, 0, 0);
}

// ---------------------------------------------------------------------------
// Dtype probe: fp32 inputs viewed as u16 have random-mantissa low halves ->
// ~22% of words decode to bf16 exponent >= 0xC8 (|v| > 2^73). bf16 N(0,1)
// data: zero such words. One thread scans 512 words (first 256 floats of z).
// ---------------------------------------------------------------------------
__global__ void detect_dtype(const unsigned short* __restrict__ z, int* __restrict__ flag)
{
    if (threadIdx.x == 0 && blockIdx.x == 0) {
        int c = 0;
        for (int i = 0; i < 512; ++i) {
            const int e = (z[i] >> 7) & 0xFF;
            c += (e >= 0xC8) ? 1 : 0;
        }
        *flag = (c > 8) ? 1 : 0;
    }
}

// ---------------------------------------------------------------------------
// Hopf trajectory. One thread per (batch b, oscillator i), 128 Euler steps in
// fp32 registers. Z[t*65536 + b*1024 + {i,512+i}] = bf16(x_t,y_t), t=0 is z1.
// z1 (output 1) written in the harness's output dtype.
// ---------------------------------------------------------------------------
__global__ __launch_bounds__(256)
void hopf_traj(const void* __restrict__ z, const void* __restrict__ omega,
               const void* __restrict__ bc, const int* __restrict__ flag,
               __hip_bfloat16* __restrict__ Z, char* __restrict__ dout)
{
    const int f32 = *flag;
    const int tid = blockIdx.x * 256 + threadIdx.x;   // 32768 threads
    const int b = tid >> 9;
    const int i = tid & 511;
    float x = ldin(z, b * 1024 + i, f32);
    float y = ldin(z, b * 1024 + 512 + i, f32);
    const float om = ldin(omega, b, f32);
    const float bb = ldin(bc, b * 512 + i, f32);
    const float w  = om * (float)(i + 1);
    __hip_bfloat16* zt = Z + b * 1024 + i;
    for (int t = 0; t < 128; ++t) {
        const float r2 = x * x + y * y;
        const float f  = bb - r2;
        const float dx = f * x - w * y;
        const float dy = f * y + w * x;
        x += 0.001f * dx;
        y += 0.001f * dy;
        zt[t * 65536]       = __float2bfloat16(x);
        zt[t * 65536 + 512] = __float2bfloat16(y);
        if (t == 0) {
            if (f32) {
                float* o = (float*)(dout + (size_t)2097152 * 4);
                o[b * 1024 + i] = x; o[b * 1024 + 512 + i] = y;
            } else {
                __hip_bfloat16* o = (__hip_bfloat16*)(dout + (size_t)2097152 * 2);
                o[b * 1024 + i] = __float2bfloat16(x);
                o[b * 1024 + 512 + i] = __float2bfloat16(y);
            }
        }
    }
}

// ---------------------------------------------------------------------------
// Build transposed combined weight WcT (N x 2*din bf16, K-contiguous):
//   n <  dout : [ Wr[:,n] | -Wi[:,n] ]      (xr block)
//   n >= dout : [ Wi[:,n'] |  Wr[:,n'] ]    (yi block), n' = n - dout
// ---------------------------------------------------------------------------
__global__ __launch_bounds__(256)
void prep_wt(const void* __restrict__ Wr, const void* __restrict__ Wi,
             const int* __restrict__ flag, __hip_bfloat16* __restrict__ dst,
             int din, int dout, int colshift)
{
    const int f32 = *flag;
    const int idx = blockIdx.x * 256 + threadIdx.x;
    const int n = idx >> colshift;
    const int k = idx & ((1 << colshift) - 1);
    float v;
    if (n < dout) {
        v = (k < din) ? ldin(Wr, k * dout + n, f32)
                      : -ldin(Wi, (k - din) * dout + n, f32);
    } else {
        const int nn = n - dout;
        v = (k < din) ? ldin(Wi, k * dout + nn, f32)
                      : ldin(Wr, (k - din) * dout + nn, f32);
    }
    dst[idx] = __float2bfloat16(v);
}

// bias layout: [0,2048)=[b0_re|b0_im], [2048,3072)=[b1_re|b1_im], [3072,3328)=b2_re
__global__ __launch_bounds__(256)
void prep_bias(const void* __restrict__ b0r, const void* __restrict__ b0i,
               const void* __restrict__ b1r, const void* __restrict__ b1i,
               const void* __restrict__ b2r, const int* __restrict__ flag,
               float* __restrict__ out)
{
    const int f32 = *flag;
    const int idx = blockIdx.x * 256 + threadIdx.x;   // 13*256 = 3328 exactly
    float v;
    if      (idx < 1024) v = ldin(b0r, idx, f32);
    else if (idx < 2048) v = ldin(b0i, idx - 1024, f32);
    else if (idx < 2560) v = ldin(b1r, idx - 2048, f32);
    else if (idx < 3072) v = ldin(b1i, idx - 2560, f32);
    else                 v = ldin(b2r, idx - 3072, f32);
    out[idx] = v;
}

// ---------------------------------------------------------------------------
// GEMM: C = tanh(A @ Bt^T + bias). A: MxK bf16 row-major, Bt: NxK bf16
// (pre-transposed). 128x128 tile, BK=32, 4 waves (2x2 of 64x64), 16x16x32
// bf16 MFMA, m97-style global_load_lds width-16 staging (linear layout).
// MODE 0: dense bf16 store (row-major N). MODE 1: final layer — scatter row
// r=t*64+b to out[b][t][c] in the dtype given by flag.
// ---------------------------------------------------------------------------
template<int MODE>
__global__ __launch_bounds__(256)
void gemm_bias_tanh(const __hip_bfloat16* __restrict__ A,
                    const __hip_bfloat16* __restrict__ Bt,
                    const float* __restrict__ bias,
                    void* __restrict__ Cv, const int* __restrict__ flag,
                    int M, int N, int K)
{
    __shared__ __align__(16) __hip_bfloat16 As[4096];   // 128 x 32
    __shared__ __align__(16) __hip_bfloat16 Bs[4096];   // 128 x 32

    const int tid  = threadIdx.x;
    const int lane = tid & 63;
    const int wave = tid >> 6;
    const int wx = wave & 1;
    const int wy = wave >> 1;
    const int m0 = blockIdx.y * 128;
    const int n0 = blockIdx.x * 128;

    // staging (linear m97 layout): chunk c holds global (row=c>>2, quad=c&3)
    const int row0 = tid >> 2, q0 = tid & 3;            // chunks 0..255
    const __hip_bfloat16* gA0 = A  + (size_t)(m0 + row0) * K + q0 * 8;
    const __hip_bfloat16* gA1 = A  + (size_t)(m0 + 64 + row0) * K + q0 * 8;  // chunks 256..511
    const __hip_bfloat16* gB0 = Bt + (size_t)(n0 + row0) * K + q0 * 8;
    const __hip_bfloat16* gB1 = Bt + (size_t)(n0 + 64 + row0) * K + q0 * 8;

    AS3 char* lAs = (AS3 char*)As;
    AS3 char* lBs = (AS3 char*)Bs;
    const int ldsw = wave * 1024;   // wave-uniform base; HW writes base + lane*16

    // fragment offsets: A[m=lane&15][k=(lane>>4)*8+j]
    const int fr = lane & 15;
    const int fq = lane >> 4;
    const int aoff = (wy * 64 + fr) * 32 + fq * 8;
    const int boff = (wx * 64 + fr) * 32 + fq * 8;

    f32x4 acc[4][4];
#pragma unroll
    for (int i = 0; i < 4; ++i)
#pragma unroll
        for (int j = 0; j < 4; ++j)
            acc[i][j] = (f32x4){0.f, 0.f, 0.f, 0.f};

    const int KT = K >> 5;
    for (int kt = 0; kt < KT; ++kt) {
        const int kk = kt << 5;
        gload_lds16(gA0 + kk, lAs + ldsw);
        gload_lds16(gA1 + kk, lAs + 4096 + ldsw);
        gload_lds16(gB0 + kk, lBs + ldsw);
        gload_lds16(gB1 + kk, lBs + 4096 + ldsw);
        __syncthreads();   // compiler drains vmcnt(0) before s_barrier

        bf16x8 af[4], bfr[4];
#pragma unroll
        for (int i = 0; i < 4; ++i) af[i]  = *(const bf16x8*)(As + aoff + i * 512);
#pragma unroll
        for (int j = 0; j < 4; ++j) bfr[j] = *(const bf16x8*)(Bs + boff + j * 512);
#pragma unroll
        for (int i = 0; i < 4; ++i)
#pragma unroll
            for (int j = 0; j < 4; ++j)
                acc[i][j] = __builtin_amdgcn_mfma_f32_16x16x32_bf16(af[i], bfr[j], acc[i][j], 0, 0, 0);
        __syncthreads();
    }

    // epilogue: C/D layout col = lane&15, row = (lane>>4)*4 + reg
    const int col_l = lane & 15;
    const int rq    = lane >> 4;
    const int f32   = (MODE == 1) ? *flag : 0;
    float bv[4];
#pragma unroll
    for (int j = 0; j < 4; ++j)
        bv[j] = bias[n0 + wx * 64 + j * 16 + col_l];

#pragma unroll
    for (int i = 0; i < 4; ++i) {
#pragma unroll
        for (int j = 0; j < 4; ++j) {
            const int gc = n0 + wx * 64 + j * 16 + col_l;
#pragma unroll
            for (int r = 0; r < 4; ++r) {
                const int gr = m0 + wy * 64 + i * 16 + rq * 4 + r;
                const float v = fast_tanh(acc[i][j][r] + bv[j]);
                if (MODE == 0) {
                    ((__hip_bfloat16*)Cv)[(size_t)gr * (size_t)N + gc] = __float2bfloat16(v);
                } else {
                    const size_t idx = (size_t)(gr & 63) * 32768 + (size_t)(gr >> 6) * 256 + (size_t)gc;
                    if (f32) ((float*)Cv)[idx] = v;
                    else     ((__hip_bfloat16*)Cv)[idx] = __float2bfloat16(v);
                }
            }
        }
    }
}

// ---------------------------------------------------------------------------
// ws layout: [0,16M) Z (8192x1024 bf16; reused as H1), [16M,48M) H0
// (8192x2048 bf16), [48M,52M) WcT0, [52M,56M) WcT1, [56M,56.5M) WcT2,
// [56.5M,+13K) bias f32, [57M] dtype flag.
// ---------------------------------------------------------------------------
extern "C" void kernel_launch(void* const* d_in, const int* in_sizes, int n_in,
                              void* d_out, int out_size, void* d_ws, size_t ws_size,
                              hipStream_t stream)
{
    (void)in_sizes; (void)n_in; (void)out_size; (void)ws_size;
    char* ws = (char*)d_ws;
    __hip_bfloat16* Z    = (__hip_bfloat16*)(ws);
    __hip_bfloat16* H0   = (__hip_bfloat16*)(ws + (16u << 20));
    __hip_bfloat16* WT0  = (__hip_bfloat16*)(ws + (48u << 20));
    __hip_bfloat16* WT1  = (__hip_bfloat16*)(ws + (52u << 20));
    __hip_bfloat16* WT2  = (__hip_bfloat16*)(ws + (56u << 20));
    float*          bias = (float*)        (ws + (56u << 20) + (512u << 10));
    int*            flag = (int*)          (ws + (57u << 20));

    detect_dtype<<<1, 64, 0, stream>>>((const unsigned short*)d_in[0], flag);
    hopf_traj<<<128, 256, 0, stream>>>(d_in[0], d_in[1], d_in[2], flag, Z, (char*)d_out);
    prep_wt<<<8192, 256, 0, stream>>>(d_in[3],  d_in[4],  flag, WT0, 512, 1024, 10);  // 2048x1024
    prep_wt<<<8192, 256, 0, stream>>>(d_in[7],  d_in[8],  flag, WT1, 1024, 512, 11);  // 1024x2048
    prep_wt<<<1024, 256, 0, stream>>>(d_in[11], d_in[12], flag, WT2, 512, 256, 10);   // 256x1024
    prep_bias<<<13, 256, 0, stream>>>(d_in[5], d_in[6], d_in[9], d_in[10], d_in[13], flag, bias);

    // G0: [x|y] (8192x1024) @ WcT0^T -> H0 (8192x2048)
    gemm_bias_tanh<0><<<dim3(16, 64), 256, 0, stream>>>(Z, WT0, bias, H0, flag, 8192, 2048, 1024);
    // G1: H0 @ WcT1^T -> H1 (8192x1024), overwrites Z (dead after G0)
    gemm_bias_tanh<0><<<dim3(8, 64), 256, 0, stream>>>(H0, WT1, bias + 2048, Z, flag, 8192, 1024, 2048);
    // G2: H1 @ WcT2^T -> out[b][t][c] (N=256), dtype per flag
    gemm_bias_tanh<1><<<dim3(2, 64), 256, 0, stream>>>(Z, WT2, bias + 3072, d_out, flag, 8192, 256, 1024);
}

// Round 3
// 219.094 us; speedup vs baseline: 1.2556x; 1.2556x over previous
//
#include <hip/hip_runtime.h>
#include <hip/hip_bf16.h>
#include <stdint.h>

#define AS1 __attribute__((address_space(1)))
#define AS3 __attribute__((address_space(3)))

typedef __bf16 bf16x8 __attribute__((ext_vector_type(8)));
typedef float f32x4 __attribute__((ext_vector_type(4)));

__device__ __forceinline__ float fast_tanh(float x) {
    float e = __expf(2.0f * x);           // inf/0 endpoints give +/-1 exactly, no NaN
    return 1.0f - 2.0f / (e + 1.0f);
}

__device__ __forceinline__ float ldin(const void* p, int idx, int f32) {
    return f32 ? ((const float*)p)[idx]
               : __bfloat162float(((const __hip_bfloat16*)p)[idx]);
}

__device__ __forceinline__ unsigned short f2bf(float v) {
    __hip_bfloat16 h = __float2bfloat16(v);
    return *(unsigned short*)&h;
}

__device__ __forceinline__ void gload_lds16(const __hip_bfloat16* g, AS3 char* l) {
    __builtin_amdgcn_global_load_lds((AS1 void*)g, (AS3 void*)l, 16, 0, 0);
}

// ---------------------------------------------------------------------------
// Dtype probe (64 lanes): fp32 data viewed as u16 -> ~22% of words have bf16
// exponent >= 0xC8. bf16 N(0,1): none.
// ---------------------------------------------------------------------------
__global__ void detect_dtype(const unsigned short* __restrict__ z, int* __restrict__ flag)
{
    const int l = threadIdx.x;
    int c = 0;
    for (int i = l; i < 512; i += 64)
        c += (((z[i] >> 7) & 0xFF) >= 0xC8) ? 1 : 0;
#pragma unroll
    for (int off = 32; off; off >>= 1) c += __shfl_down(c, off);
    if (l == 0) *flag = (c > 8) ? 1 : 0;
}

// ---------------------------------------------------------------------------
// Hopf trajectory. One thread per (b,i), 128 fp32 Euler steps.
// Z[t*65536 + b*1024 + {i,512+i}] = bf16(x_t,y_t). z1 -> d_out tail.
// ---------------------------------------------------------------------------
__global__ __launch_bounds__(256)
void hopf_traj(const void* __restrict__ z, const void* __restrict__ omega,
               const void* __restrict__ bc, const int* __restrict__ flag,
               __hip_bfloat16* __restrict__ Z, char* __restrict__ dout)
{
    const int f32 = *flag;
    const int tid = blockIdx.x * 256 + threadIdx.x;
    const int b = tid >> 9;
    const int i = tid & 511;
    float x = ldin(z, b * 1024 + i, f32);
    float y = ldin(z, b * 1024 + 512 + i, f32);
    const float om = ldin(omega, b, f32);
    const float bb = ldin(bc, b * 512 + i, f32);
    const float w  = om * (float)(i + 1);
    __hip_bfloat16* zt = Z + b * 1024 + i;
    for (int t = 0; t < 128; ++t) {
        const float r2 = x * x + y * y;
        const float f  = bb - r2;
        const float dx = f * x - w * y;
        const float dy = f * y + w * x;
        x += 0.001f * dx;
        y += 0.001f * dy;
        zt[t * 65536]       = __float2bfloat16(x);
        zt[t * 65536 + 512] = __float2bfloat16(y);
        if (t == 0) {
            if (f32) {
                float* o = (float*)(dout + (size_t)2097152 * 4);
                o[b * 1024 + i] = x; o[b * 1024 + 512 + i] = y;
            } else {
                __hip_bfloat16* o = (__hip_bfloat16*)(dout + (size_t)2097152 * 2);
                o[b * 1024 + i] = __float2bfloat16(x);
                o[b * 1024 + 512 + i] = __float2bfloat16(y);
            }
        }
    }
}

// ---------------------------------------------------------------------------
// Fused prep: blocks [0,512) WT0, [512,1024) WT1, [1024,1088) WT2 do 64x64
// LDS-transpose tiles (coalesced both sides); blocks [1088,1101) build bias.
// WcT[n][k]: n<dout: [Wr | -Wi]; n>=dout: [Wi | Wr] (cols: k<din | k>=din).
// ---------------------------------------------------------------------------
__global__ __launch_bounds__(256)
void prep_fused(const void* __restrict__ W0r, const void* __restrict__ W0i,
                const void* __restrict__ W1r, const void* __restrict__ W1i,
                const void* __restrict__ W2r, const void* __restrict__ W2i,
                const void* __restrict__ b0r, const void* __restrict__ b0i,
                const void* __restrict__ b1r, const void* __restrict__ b1i,
                const void* __restrict__ b2r, const int* __restrict__ flag,
                __hip_bfloat16* __restrict__ WT0, __hip_bfloat16* __restrict__ WT1,
                __hip_bfloat16* __restrict__ WT2, float* __restrict__ biasOut)
{
    const int bid = blockIdx.x;
    const int t   = threadIdx.x;
    const int f32 = *flag;

    if (bid >= 1088) {   // bias path
        const int idx = (bid - 1088) * 256 + t;   // [0,3328)
        float v;
        if      (idx < 1024) v = ldin(b0r, idx, f32);
        else if (idx < 2048) v = ldin(b0i, idx - 1024, f32);
        else if (idx < 2560) v = ldin(b1r, idx - 2048, f32);
        else if (idx < 3072) v = ldin(b1i, idx - 2560, f32);
        else                 v = ldin(b2r, idx - 3072, f32);
        biasOut[idx] = v;
        return;
    }

    __shared__ float T[64][65];

    int din, dout, KT, nt, kt;
    const void *Wr, *Wi;
    __hip_bfloat16* dst;
    if (bid < 512)       { din = 512;  dout = 1024; KT = 1024; Wr = W0r; Wi = W0i; dst = WT0;
                           nt = bid >> 4;            kt = bid & 15; }
    else if (bid < 1024) { din = 1024; dout = 512;  KT = 2048; Wr = W1r; Wi = W1i; dst = WT1;
                           nt = (bid - 512) >> 5;    kt = (bid - 512) & 31; }
    else                 { din = 512;  dout = 256;  KT = 1024; Wr = W2r; Wi = W2i; dst = WT2;
                           nt = (bid - 1024) >> 4;   kt = (bid - 1024) & 15; }

    const int n0 = nt * 64, k0 = kt * 64;
    const void* src; float sg; int col0, krel;
    if (n0 < dout) {
        col0 = n0;
        if (k0 < din) { src = Wr; sg =  1.f; krel = k0; }
        else          { src = Wi; sg = -1.f; krel = k0 - din; }
    } else {
        col0 = n0 - dout;
        if (k0 < din) { src = Wi; sg =  1.f; krel = k0; }
        else          { src = Wr; sg =  1.f; krel = k0 - din; }
    }

    const int lr = t >> 4;          // 0..15
    const int lc = t & 15;          // 0..15
#pragma unroll
    for (int p = 0; p < 4; ++p) {
        const int r = p * 16 + lr;              // k-dim row 0..63
        const int c = lc * 4;                   // n-dim col
        const size_t gi = (size_t)(krel + r) * dout + col0 + c;
        float v0, v1, v2, v3;
        if (f32) {
            float4 v = *(const float4*)((const float*)src + gi);
            v0 = v.x; v1 = v.y; v2 = v.z; v3 = v.w;
        } else {
            ushort4 u = *(const ushort4*)((const unsigned short*)src + gi);
            __hip_bfloat16 h0, h1, h2, h3;
            *(unsigned short*)&h0 = u.x; *(unsigned short*)&h1 = u.y;
            *(unsigned short*)&h2 = u.z; *(unsigned short*)&h3 = u.w;
            v0 = __bfloat162float(h0); v1 = __bfloat162float(h1);
            v2 = __bfloat162float(h2); v3 = __bfloat162float(h3);
        }
        T[r][c] = sg * v0; T[r][c + 1] = sg * v1;
        T[r][c + 2] = sg * v2; T[r][c + 3] = sg * v3;
    }
    __syncthreads();
#pragma unroll
    for (int q = 0; q < 4; ++q) {
        const int n = q * 16 + lr;              // n-dim row of WcT
        const int k8 = lc;                      // 4-elem chunk along k
        ushort4 u;
        u.x = f2bf(T[k8 * 4 + 0][n]); u.y = f2bf(T[k8 * 4 + 1][n]);
        u.z = f2bf(T[k8 * 4 + 2][n]); u.w = f2bf(T[k8 * 4 + 3][n]);
        *(ushort4*)((unsigned short*)dst + (size_t)(n0 + n) * KT + k0 + k8 * 4) = u;
    }
}

// ---------------------------------------------------------------------------
// GEMM: C = tanh(A @ Bt^T + bias). MT x 128 tile, BK=64, 4 waves (2x2),
// 16x16x32 bf16 MFMA. XOR-swizzled LDS: 16B chunk at (row, slot s) holds
// global k-quad q = s ^ (row&7) -> ds_read_b128 fragment reads hit 8 distinct
// bank windows per quarter-wave (2 lanes/window = free).
// MODE 1: scatter row r=t*64+b -> out[b][t][c], dtype per flag.
// ---------------------------------------------------------------------------
template<int MT, int MODE>
__global__ __launch_bounds__(256)
void gemm_bias_tanh(const __hip_bfloat16* __restrict__ A,
                    const __hip_bfloat16* __restrict__ Bt,
                    const float* __restrict__ bias,
                    void* __restrict__ Cv, const int* __restrict__ flag,
                    int M, int N, int K)
{
    constexpr int AI = MT / 32;   // A staging insts/wave == A-frag count/wave
    __shared__ __align__(16) __hip_bfloat16 As[MT * 64];
    __shared__ __align__(16) __hip_bfloat16 Bs[128 * 64];

    const int tid = threadIdx.x, lane = tid & 63, w = tid >> 6;
    const int wx = w & 1, wy = w >> 1;
    const int m0 = blockIdx.y * MT;
    const int n0 = blockIdx.x * 128;

    // staging addresses (per-thread constant): chunk row/slot -> global quad
    const int sl = lane & 7, lr8 = lane >> 3;
    const __hip_bfloat16* gA[AI];
    const __hip_bfloat16* gB[4];
#pragma unroll
    for (int p = 0; p < AI; ++p) {
        const int row = w * (MT / 4) + p * 8 + lr8;
        const int q = sl ^ (row & 7);
        gA[p] = A + (size_t)(m0 + row) * K + q * 8;
    }
#pragma unroll
    for (int p = 0; p < 4; ++p) {
        const int row = w * 32 + p * 8 + lr8;
        const int q = sl ^ (row & 7);
        gB[p] = Bt + (size_t)(n0 + row) * K + q * 8;
    }
    AS3 char* lA = (AS3 char*)As + w * (MT * 32);
    AS3 char* lB = (AS3 char*)Bs + w * 4096;

    // fragment read offsets: row R, k-quad KQ=ks*4+fq, slot = KQ ^ (R&7)
    const int fr = lane & 15, fq = lane >> 4;
    const int swz = (fq ^ (fr & 7)) * 8;      // element offset of slot, ks=0
    const int arow = wy * (MT / 2) + fr;
    const int brow = wx * 64 + fr;

    f32x4 acc[AI][4];
#pragma unroll
    for (int i = 0; i < AI; ++i)
#pragma unroll
        for (int j = 0; j < 4; ++j)
            acc[i][j] = (f32x4){0.f, 0.f, 0.f, 0.f};

    const int NKT = K >> 6;
    for (int kt = 0; kt < NKT; ++kt) {
        const int kk = kt << 6;
#pragma unroll
        for (int p = 0; p < AI; ++p) gload_lds16(gA[p] + kk, lA + p * 1024);
#pragma unroll
        for (int p = 0; p < 4; ++p)  gload_lds16(gB[p] + kk, lB + p * 1024);
        __syncthreads();
#pragma unroll
        for (int ks = 0; ks < 2; ++ks) {
            const int so = swz ^ (ks << 5);   // (swz0 ^ ks*4) * 8 elements
            bf16x8 af[AI], bv[4];
#pragma unroll
            for (int i = 0; i < AI; ++i)
                af[i] = *(const bf16x8*)(As + (arow + i * 16) * 64 + so);
#pragma unroll
            for (int j = 0; j < 4; ++j)
                bv[j] = *(const bf16x8*)(Bs + (brow + j * 16) * 64 + so);
#pragma unroll
            for (int i = 0; i < AI; ++i)
#pragma unroll
                for (int j = 0; j < 4; ++j)
                    acc[i][j] = __builtin_amdgcn_mfma_f32_16x16x32_bf16(af[i], bv[j], acc[i][j], 0, 0, 0);
        }
        __syncthreads();
    }

    // epilogue: C/D layout col = lane&15, row = (lane>>4)*4 + reg
    const int col_l = lane & 15;
    const int rq    = lane >> 4;
    const int f32   = (MODE == 1) ? *flag : 0;
    float bvv[4];
#pragma unroll
    for (int j = 0; j < 4; ++j)
        bvv[j] = bias[n0 + wx * 64 + j * 16 + col_l];

#pragma unroll
    for (int i = 0; i < AI; ++i) {
#pragma unroll
        for (int j = 0; j < 4; ++j) {
            const int gc = n0 + wx * 64 + j * 16 + col_l;
#pragma unroll
            for (int r = 0; r < 4; ++r) {
                const int gr = m0 + wy * (MT / 2) + i * 16 + rq * 4 + r;
                const float v = fast_tanh(acc[i][j][r] + bvv[j]);
                if (MODE == 0) {
                    ((__hip_bfloat16*)Cv)[(size_t)gr * (size_t)N + gc] = __float2bfloat16(v);
                } else {
                    const size_t idx = (size_t)(gr & 63) * 32768 + (size_t)(gr >> 6) * 256 + (size_t)gc;
                    if (f32) ((float*)Cv)[idx] = v;
                    else     ((__hip_bfloat16*)Cv)[idx] = __float2bfloat16(v);
                }
            }
        }
    }
}

// ---------------------------------------------------------------------------
// ws: [0,16M) Z (8192x1024 bf16; reused as H1), [16M,48M) H0 (8192x2048),
// [48M) WT0 4M, [52M) WT1 4M, [56M) WT2 0.5M, [56M+512K) bias f32, [57M) flag.
// ---------------------------------------------------------------------------
extern "C" void kernel_launch(void* const* d_in, const int* in_sizes, int n_in,
                              void* d_out, int out_size, void* d_ws, size_t ws_size,
                              hipStream_t stream)
{
    (void)in_sizes; (void)n_in; (void)out_size; (void)ws_size;
    char* ws = (char*)d_ws;
    __hip_bfloat16* Z    = (__hip_bfloat16*)(ws);
    __hip_bfloat16* H0   = (__hip_bfloat16*)(ws + (16u << 20));
    __hip_bfloat16* WT0  = (__hip_bfloat16*)(ws + (48u << 20));
    __hip_bfloat16* WT1  = (__hip_bfloat16*)(ws + (52u << 20));
    __hip_bfloat16* WT2  = (__hip_bfloat16*)(ws + (56u << 20));
    float*          bias = (float*)        (ws + (56u << 20) + (512u << 10));
    int*            flag = (int*)          (ws + (57u << 20));

    detect_dtype<<<1, 64, 0, stream>>>((const unsigned short*)d_in[0], flag);
    hopf_traj<<<128, 256, 0, stream>>>(d_in[0], d_in[1], d_in[2], flag, Z, (char*)d_out);
    prep_fused<<<1101, 256, 0, stream>>>(d_in[3], d_in[4], d_in[7], d_in[8], d_in[11], d_in[12],
                                         d_in[5], d_in[6], d_in[9], d_in[10], d_in[13], flag,
                                         WT0, WT1, WT2, bias);

    // G0: Z (8192x1024) @ WcT0^T -> H0 (8192x2048)
    gemm_bias_tanh<128, 0><<<dim3(16, 64), 256, 0, stream>>>(Z, WT0, bias, H0, flag, 8192, 2048, 1024);
    // G1: H0 @ WcT1^T -> H1 (8192x1024), overwrites Z
    gemm_bias_tanh<128, 0><<<dim3(8, 64), 256, 0, stream>>>(H0, WT1, bias + 2048, Z, flag, 8192, 1024, 2048);
    // G2: H1 @ WcT2^T -> out[b][t][c] (N=256), MT=64 -> 256 blocks
    gemm_bias_tanh<64, 1><<<dim3(2, 128), 256, 0, stream>>>(Z, WT2, bias + 3072, d_out, flag, 8192, 256, 1024);
}

// Round 4
// 210.927 us; speedup vs baseline: 1.3042x; 1.0387x over previous
//
#include <hip/hip_runtime.h>
#include <hip/hip_bf16.h>
#include <stdint.h>

#define AS1 __attribute__((address_space(1)))
#define AS3 __attribute__((address_space(3)))

typedef __bf16 bf16x8 __attribute__((ext_vector_type(8)));
typedef float f32x4 __attribute__((ext_vector_type(4)));

__device__ __forceinline__ float fast_tanh(float x) {
    float e = __expf(2.0f * x);           // inf/0 endpoints give +/-1 exactly, no NaN
    return 1.0f - 2.0f / (e + 1.0f);
}

__device__ __forceinline__ float ldin(const void* p, int idx, int f32) {
    return f32 ? ((const float*)p)[idx]
               : __bfloat162float(((const __hip_bfloat16*)p)[idx]);
}

__device__ __forceinline__ unsigned short f2bf(float v) {
    __hip_bfloat16 h = __float2bfloat16(v);
    return *(unsigned short*)&h;
}

__device__ __forceinline__ void gload_lds16(const __hip_bfloat16* g, AS3 char* l) {
    __builtin_amdgcn_global_load_lds((AS1 void*)g, (AS3 void*)l, 16, 0, 0);
}

// ---------------------------------------------------------------------------
// Fused setup: one kernel, 1229 blocks.
//   [0,128)     : Hopf trajectory (one thread per (b,i), 128 fp32 Euler steps)
//   [128,1216)  : weight transpose tiles (WT0 512, WT1 512, WT2 64)
//   [1216,1229) : bias build; block 1216 also publishes dtype flag to ws
// Every block runs an inline dtype probe on z's first 512 u16 words (1 KB,
// L2-hot): fp32 data -> ~22% of words have bf16-exponent >= 0xC8; bf16: none.
// ---------------------------------------------------------------------------
__global__ __launch_bounds__(256)
void setup_all(const void* __restrict__ z, const void* __restrict__ omega,
               const void* __restrict__ bc,
               const void* __restrict__ W0r, const void* __restrict__ W0i,
               const void* __restrict__ W1r, const void* __restrict__ W1i,
               const void* __restrict__ W2r, const void* __restrict__ W2i,
               const void* __restrict__ b0r, const void* __restrict__ b0i,
               const void* __restrict__ b1r, const void* __restrict__ b1i,
               const void* __restrict__ b2r,
               __hip_bfloat16* __restrict__ Z, __hip_bfloat16* __restrict__ WT0,
               __hip_bfloat16* __restrict__ WT1, __hip_bfloat16* __restrict__ WT2,
               float* __restrict__ biasOut, int* __restrict__ flagOut,
               char* __restrict__ dout)
{
    __shared__ float T[64][65];
    __shared__ int sflag;
    const int t   = threadIdx.x;
    const int bid = blockIdx.x;

    if (t == 0) sflag = 0;
    __syncthreads();
    {
        const unsigned short* zz = (const unsigned short*)z;
        const int c = ((((zz[t] >> 7) & 0xFF) >= 0xC8) ? 1 : 0)
                    + ((((zz[t + 256] >> 7) & 0xFF) >= 0xC8) ? 1 : 0);
        if (c) atomicAdd(&sflag, c);
    }
    __syncthreads();
    const int f32 = (sflag > 8) ? 1 : 0;

    if (bid < 128) {
        // ----- Hopf trajectory -----
        const int tid = bid * 256 + t;
        const int b = tid >> 9;
        const int i = tid & 511;
        float x = ldin(z, b * 1024 + i, f32);
        float y = ldin(z, b * 1024 + 512 + i, f32);
        const float om = ldin(omega, b, f32);
        const float bb = ldin(bc, b * 512 + i, f32);
        const float w  = om * (float)(i + 1);
        __hip_bfloat16* zt = Z + b * 1024 + i;
        for (int s = 0; s < 128; ++s) {
            const float r2 = x * x + y * y;
            const float f  = bb - r2;
            const float dx = f * x - w * y;
            const float dy = f * y + w * x;
            x += 0.001f * dx;
            y += 0.001f * dy;
            zt[s * 65536]       = __float2bfloat16(x);
            zt[s * 65536 + 512] = __float2bfloat16(y);
            if (s == 0) {
                if (f32) {
                    float* o = (float*)(dout + (size_t)2097152 * 4);
                    o[b * 1024 + i] = x; o[b * 1024 + 512 + i] = y;
                } else {
                    __hip_bfloat16* o = (__hip_bfloat16*)(dout + (size_t)2097152 * 2);
                    o[b * 1024 + i] = __float2bfloat16(x);
                    o[b * 1024 + 512 + i] = __float2bfloat16(y);
                }
            }
        }
        return;
    }

    if (bid >= 1216) {
        // ----- bias + flag publish -----
        if (bid == 1216 && t == 0) *flagOut = f32;
        const int idx = (bid - 1216) * 256 + t;   // [0,3328)
        float v;
        if      (idx < 1024) v = ldin(b0r, idx, f32);
        else if (idx < 2048) v = ldin(b0i, idx - 1024, f32);
        else if (idx < 2560) v = ldin(b1r, idx - 2048, f32);
        else if (idx < 3072) v = ldin(b1i, idx - 2560, f32);
        else                 v = ldin(b2r, idx - 3072, f32);
        biasOut[idx] = v;
        return;
    }

    // ----- weight transpose: WcT[n][k] = n<dout ? [Wr|-Wi] : [Wi|Wr] -----
    const int wbid = bid - 128;   // [0,1088)
    int din, dout_, KT, nt, kt;
    const void *Wr, *Wi;
    __hip_bfloat16* dst;
    if (wbid < 512)       { din = 512;  dout_ = 1024; KT = 1024; Wr = W0r; Wi = W0i; dst = WT0;
                            nt = wbid >> 4;           kt = wbid & 15; }
    else if (wbid < 1024) { din = 1024; dout_ = 512;  KT = 2048; Wr = W1r; Wi = W1i; dst = WT1;
                            nt = (wbid - 512) >> 5;   kt = (wbid - 512) & 31; }
    else                  { din = 512;  dout_ = 256;  KT = 1024; Wr = W2r; Wi = W2i; dst = WT2;
                            nt = (wbid - 1024) >> 4;  kt = (wbid - 1024) & 15; }

    const int n0 = nt * 64, k0 = kt * 64;
    const void* src; float sg; int col0, krel;
    if (n0 < dout_) {
        col0 = n0;
        if (k0 < din) { src = Wr; sg =  1.f; krel = k0; }
        else          { src = Wi; sg = -1.f; krel = k0 - din; }
    } else {
        col0 = n0 - dout_;
        if (k0 < din) { src = Wi; sg =  1.f; krel = k0; }
        else          { src = Wr; sg =  1.f; krel = k0 - din; }
    }

    const int lr = t >> 4;          // 0..15
    const int lc = t & 15;          // 0..15
#pragma unroll
    for (int p = 0; p < 4; ++p) {
        const int r = p * 16 + lr;              // k-dim row 0..63
        const int c = lc * 4;                   // n-dim col
        const size_t gi = (size_t)(krel + r) * dout_ + col0 + c;
        float v0, v1, v2, v3;
        if (f32) {
            float4 v = *(const float4*)((const float*)src + gi);
            v0 = v.x; v1 = v.y; v2 = v.z; v3 = v.w;
        } else {
            ushort4 u = *(const ushort4*)((const unsigned short*)src + gi);
            __hip_bfloat16 h0, h1, h2, h3;
            *(unsigned short*)&h0 = u.x; *(unsigned short*)&h1 = u.y;
            *(unsigned short*)&h2 = u.z; *(unsigned short*)&h3 = u.w;
            v0 = __bfloat162float(h0); v1 = __bfloat162float(h1);
            v2 = __bfloat162float(h2); v3 = __bfloat162float(h3);
        }
        T[r][c] = sg * v0; T[r][c + 1] = sg * v1;
        T[r][c + 2] = sg * v2; T[r][c + 3] = sg * v3;
    }
    __syncthreads();
#pragma unroll
    for (int q = 0; q < 4; ++q) {
        const int n = q * 16 + lr;              // n-dim row of WcT
        const int k8 = lc;                      // 4-elem chunk along k
        ushort4 u;
        u.x = f2bf(T[k8 * 4 + 0][n]); u.y = f2bf(T[k8 * 4 + 1][n]);
        u.z = f2bf(T[k8 * 4 + 2][n]); u.w = f2bf(T[k8 * 4 + 3][n]);
        *(ushort4*)((unsigned short*)dst + (size_t)(n0 + n) * KT + k0 + k8 * 4) = u;
    }
}

// ---------------------------------------------------------------------------
// GEMM: C = tanh(A @ Bt^T + bias). MT x 128 tile, BK=64, 4 waves (2x2),
// 16x16x32 bf16 MFMA, XOR-swizzled LDS (slot = q ^ (row&7), conflict-free).
// 1-D grid with XCD-aware mapping (GX = N/128 n-tiles, template):
//   xcd = bid&7 owns n-tiles [xcd*GX/8, (xcd+1)*GX/8) for ALL m-tiles ->
//   weights slice (<=512 KB) resident in that XCD's L2; adjacent co-resident
//   blocks share A-tiles. GX<8 falls back to plain mapping.
// MODE 1: scatter row r=t*64+b -> out[b][t][c], dtype per flag.
// ---------------------------------------------------------------------------
template<int MT, int GX, int MODE>
__global__ __launch_bounds__(256)
void gemm_bias_tanh(const __hip_bfloat16* __restrict__ A,
                    const __hip_bfloat16* __restrict__ Bt,
                    const float* __restrict__ bias,
                    void* __restrict__ Cv, const int* __restrict__ flag,
                    int M, int N, int K)
{
    constexpr int AI = MT / 32;
    __shared__ __align__(16) __hip_bfloat16 As[MT * 64];
    __shared__ __align__(16) __hip_bfloat16 Bs[128 * 64];

    const int tid = threadIdx.x, lane = tid & 63, w = tid >> 6;
    const int wx = w & 1, wy = w >> 1;

    constexpr int XG = GX >> 3;
    int nt, mt;
    const int bid = blockIdx.x;
    if constexpr (XG > 0) {
        const int xcd = bid & 7, r = bid >> 3;
        nt = xcd * XG + (r % XG);
        mt = r / XG;
    } else {
        nt = bid % GX;
        mt = bid / GX;
    }
    const int m0 = mt * MT;
    const int n0 = nt * 128;

    // staging: chunk (row, slot s) holds global k-quad q = s ^ (row&7)
    const int sl = lane & 7, lr8 = lane >> 3;
    const __hip_bfloat16* gA[AI];
    const __hip_bfloat16* gB[4];
#pragma unroll
    for (int p = 0; p < AI; ++p) {
        const int row = w * (MT / 4) + p * 8 + lr8;
        const int q = sl ^ (row & 7);
        gA[p] = A + (size_t)(m0 + row) * K + q * 8;
    }
#pragma unroll
    for (int p = 0; p < 4; ++p) {
        const int row = w * 32 + p * 8 + lr8;
        const int q = sl ^ (row & 7);
        gB[p] = Bt + (size_t)(n0 + row) * K + q * 8;
    }
    AS3 char* lA = (AS3 char*)As + w * (MT * 32);
    AS3 char* lB = (AS3 char*)Bs + w * 4096;

    // fragment reads: row R, k-quad KQ = ks*4+fq, slot = KQ ^ (R&7)
    const int fr = lane & 15, fq = lane >> 4;
    const int swz = (fq ^ (fr & 7)) * 8;
    const int arow = wy * (MT / 2) + fr;
    const int brow = wx * 64 + fr;

    f32x4 acc[AI][4];
#pragma unroll
    for (int i = 0; i < AI; ++i)
#pragma unroll
        for (int j = 0; j < 4; ++j)
            acc[i][j] = (f32x4){0.f, 0.f, 0.f, 0.f};

    const int NKT = K >> 6;
    for (int kt2 = 0; kt2 < NKT; ++kt2) {
        const int kk = kt2 << 6;
#pragma unroll
        for (int p = 0; p < AI; ++p) gload_lds16(gA[p] + kk, lA + p * 1024);
#pragma unroll
        for (int p = 0; p < 4; ++p)  gload_lds16(gB[p] + kk, lB + p * 1024);
        __syncthreads();
#pragma unroll
        for (int ks = 0; ks < 2; ++ks) {
            const int so = swz ^ (ks << 5);
            bf16x8 af[AI], bv[4];
#pragma unroll
            for (int i = 0; i < AI; ++i)
                af[i] = *(const bf16x8*)(As + (arow + i * 16) * 64 + so);
#pragma unroll
            for (int j = 0; j < 4; ++j)
                bv[j] = *(const bf16x8*)(Bs + (brow + j * 16) * 64 + so);
#pragma unroll
            for (int i = 0; i < AI; ++i)
#pragma unroll
                for (int j = 0; j < 4; ++j)
                    acc[i][j] = __builtin_amdgcn_mfma_f32_16x16x32_bf16(af[i], bv[j], acc[i][j], 0, 0, 0);
        }
        __syncthreads();
    }

    // epilogue: C/D layout col = lane&15, row = (lane>>4)*4 + reg
    const int col_l = lane & 15;
    const int rq    = lane >> 4;
    const int f32   = (MODE == 1) ? *flag : 0;
    float bvv[4];
#pragma unroll
    for (int j = 0; j < 4; ++j)
        bvv[j] = bias[n0 + wx * 64 + j * 16 + col_l];

#pragma unroll
    for (int i = 0; i < AI; ++i) {
#pragma unroll
        for (int j = 0; j < 4; ++j) {
            const int gc = n0 + wx * 64 + j * 16 + col_l;
#pragma unroll
            for (int r = 0; r < 4; ++r) {
                const int gr = m0 + wy * (MT / 2) + i * 16 + rq * 4 + r;
                const float v = fast_tanh(acc[i][j][r] + bvv[j]);
                if (MODE == 0) {
                    ((__hip_bfloat16*)Cv)[(size_t)gr * (size_t)N + gc] = __float2bfloat16(v);
                } else {
                    const size_t idx = (size_t)(gr & 63) * 32768 + (size_t)(gr >> 6) * 256 + (size_t)gc;
                    if (f32) ((float*)Cv)[idx] = v;
                    else     ((__hip_bfloat16*)Cv)[idx] = __float2bfloat16(v);
                }
            }
        }
    }
}

// ---------------------------------------------------------------------------
// ws: [0,16M) Z (8192x1024 bf16; reused as H1), [16M,48M) H0 (8192x2048),
// [48M) WT0 4M, [52M) WT1 4M, [56M) WT2 0.5M, [56M+512K) bias f32, [57M) flag.
// ---------------------------------------------------------------------------
extern "C" void kernel_launch(void* const* d_in, const int* in_sizes, int n_in,
                              void* d_out, int out_size, void* d_ws, size_t ws_size,
                              hipStream_t stream)
{
    (void)in_sizes; (void)n_in; (void)out_size; (void)ws_size;
    char* ws = (char*)d_ws;
    __hip_bfloat16* Z    = (__hip_bfloat16*)(ws);
    __hip_bfloat16* H0   = (__hip_bfloat16*)(ws + (16u << 20));
    __hip_bfloat16* WT0  = (__hip_bfloat16*)(ws + (48u << 20));
    __hip_bfloat16* WT1  = (__hip_bfloat16*)(ws + (52u << 20));
    __hip_bfloat16* WT2  = (__hip_bfloat16*)(ws + (56u << 20));
    float*          bias = (float*)        (ws + (56u << 20) + (512u << 10));
    int*            flag = (int*)          (ws + (57u << 20));

    setup_all<<<1229, 256, 0, stream>>>(d_in[0], d_in[1], d_in[2],
                                        d_in[3], d_in[4], d_in[7], d_in[8], d_in[11], d_in[12],
                                        d_in[5], d_in[6], d_in[9], d_in[10], d_in[13],
                                        Z, WT0, WT1, WT2, bias, flag, (char*)d_out);

    // G0: Z (8192x1024) @ WcT0^T -> H0 (8192x2048). GX=16 n-tiles, 1024 blocks.
    gemm_bias_tanh<128, 16, 0><<<1024, 256, 0, stream>>>(Z, WT0, bias, H0, flag, 8192, 2048, 1024);
    // G1: H0 @ WcT1^T -> H1 (8192x1024), overwrites Z. MT=64 -> 1024 blocks, GX=8.
    gemm_bias_tanh<64, 8, 0><<<1024, 256, 0, stream>>>(H0, WT1, bias + 2048, Z, flag, 8192, 1024, 2048);
    // G2: H1 @ WcT2^T -> out[b][t][c] (N=256). MT=64, GX=2 -> 256 blocks.
    gemm_bias_tanh<64, 2, 1><<<256, 256, 0, stream>>>(Z, WT2, bias + 3072, d_out, flag, 8192, 256, 1024);
}

// Round 6
// 208.576 us; speedup vs baseline: 1.3189x; 1.0113x over previous
//
#include <hip/hip_runtime.h>
#include <hip/hip_bf16.h>
#include <stdint.h>

#define AS1 __attribute__((address_space(1)))
#define AS3 __attribute__((address_space(3)))

typedef __bf16 bf16x8 __attribute__((ext_vector_type(8)));
typedef float f32x4 __attribute__((ext_vector_type(4)));

__device__ __forceinline__ float fast_tanh(float x) {
    float e = __expf(2.0f * x);           // inf/0 endpoints give +/-1 exactly, no NaN
    return 1.0f - 2.0f / (e + 1.0f);
}

__device__ __forceinline__ float ldin(const void* p, int idx, int f32) {
    return f32 ? ((const float*)p)[idx]
               : __bfloat162float(((const __hip_bfloat16*)p)[idx]);
}

__device__ __forceinline__ unsigned short f2bf(float v) {
    __hip_bfloat16 h = __float2bfloat16(v);
    return *(unsigned short*)&h;
}

__device__ __forceinline__ void gload_lds16(const __hip_bfloat16* g, AS3 char* l) {
    __builtin_amdgcn_global_load_lds((AS1 void*)g, (AS3 void*)l, 16, 0, 0);
}

// ---------------------------------------------------------------------------
// Fused setup (R4, measured-good): 1229 blocks.
//   [0,128) hopf | [128,1216) weight transpose | [1216,1229) bias (+flag)
// Per-block inline dtype probe on z's first 512 u16 words.
// ---------------------------------------------------------------------------
__global__ __launch_bounds__(256)
void setup_all(const void* __restrict__ z, const void* __restrict__ omega,
               const void* __restrict__ bc,
               const void* __restrict__ W0r, const void* __restrict__ W0i,
               const void* __restrict__ W1r, const void* __restrict__ W1i,
               const void* __restrict__ W2r, const void* __restrict__ W2i,
               const void* __restrict__ b0r, const void* __restrict__ b0i,
               const void* __restrict__ b1r, const void* __restrict__ b1i,
               const void* __restrict__ b2r,
               __hip_bfloat16* __restrict__ Z, __hip_bfloat16* __restrict__ WT0,
               __hip_bfloat16* __restrict__ WT1, __hip_bfloat16* __restrict__ WT2,
               float* __restrict__ biasOut, int* __restrict__ flagOut,
               char* __restrict__ dout)
{
    __shared__ float T[64][65];
    __shared__ int sflag;
    const int t   = threadIdx.x;
    const int bid = blockIdx.x;

    if (t == 0) sflag = 0;
    __syncthreads();
    {
        const unsigned short* zz = (const unsigned short*)z;
        const int c = ((((zz[t] >> 7) & 0xFF) >= 0xC8) ? 1 : 0)
                    + ((((zz[t + 256] >> 7) & 0xFF) >= 0xC8) ? 1 : 0);
        if (c) atomicAdd(&sflag, c);
    }
    __syncthreads();
    const int f32 = (sflag > 8) ? 1 : 0;

    if (bid < 128) {
        // ----- Hopf trajectory: one thread per (b,i), 128 fp32 Euler steps
        const int tid = bid * 256 + t;
        const int b = tid >> 9;
        const int i = tid & 511;
        float x = ldin(z, b * 1024 + i, f32);
        float y = ldin(z, b * 1024 + 512 + i, f32);
        const float om = ldin(omega, b, f32);
        const float bb = ldin(bc, b * 512 + i, f32);
        const float w  = om * (float)(i + 1);
        __hip_bfloat16* zt = Z + b * 1024 + i;
        for (int s = 0; s < 128; ++s) {
            const float r2 = x * x + y * y;
            const float f  = bb - r2;
            const float dx = f * x - w * y;
            const float dy = f * y + w * x;
            x += 0.001f * dx;
            y += 0.001f * dy;
            zt[s * 65536]       = __float2bfloat16(x);
            zt[s * 65536 + 512] = __float2bfloat16(y);
            if (s == 0) {
                if (f32) {
                    float* o = (float*)(dout + (size_t)2097152 * 4);
                    o[b * 1024 + i] = x; o[b * 1024 + 512 + i] = y;
                } else {
                    __hip_bfloat16* o = (__hip_bfloat16*)(dout + (size_t)2097152 * 2);
                    o[b * 1024 + i] = __float2bfloat16(x);
                    o[b * 1024 + 512 + i] = __float2bfloat16(y);
                }
            }
        }
        return;
    }

    if (bid >= 1216) {
        if (bid == 1216 && t == 0) *flagOut = f32;
        const int idx = (bid - 1216) * 256 + t;   // [0,3328)
        float v;
        if      (idx < 1024) v = ldin(b0r, idx, f32);
        else if (idx < 2048) v = ldin(b0i, idx - 1024, f32);
        else if (idx < 2560) v = ldin(b1r, idx - 2048, f32);
        else if (idx < 3072) v = ldin(b1i, idx - 2560, f32);
        else                 v = ldin(b2r, idx - 3072, f32);
        biasOut[idx] = v;
        return;
    }

    // ----- weight transpose: WcT[n][k] = n<dout ? [Wr|-Wi] : [Wi|Wr]
    const int wbid = bid - 128;   // [0,1088)
    int din, dout_, KT, nt, kt;
    const void *Wr, *Wi;
    __hip_bfloat16* dst;
    if (wbid < 512)       { din = 512;  dout_ = 1024; KT = 1024; Wr = W0r; Wi = W0i; dst = WT0;
                            nt = wbid >> 4;           kt = wbid & 15; }
    else if (wbid < 1024) { din = 1024; dout_ = 512;  KT = 2048; Wr = W1r; Wi = W1i; dst = WT1;
                            nt = (wbid - 512) >> 5;   kt = (wbid - 512) & 31; }
    else                  { din = 512;  dout_ = 256;  KT = 1024; Wr = W2r; Wi = W2i; dst = WT2;
                            nt = (wbid - 1024) >> 4;  kt = (wbid - 1024) & 15; }

    const int n0 = nt * 64, k0 = kt * 64;
    const void* src; float sg; int col0, krel;
    if (n0 < dout_) {
        col0 = n0;
        if (k0 < din) { src = Wr; sg =  1.f; krel = k0; }
        else          { src = Wi; sg = -1.f; krel = k0 - din; }
    } else {
        col0 = n0 - dout_;
        if (k0 < din) { src = Wi; sg =  1.f; krel = k0; }
        else          { src = Wr; sg =  1.f; krel = k0 - din; }
    }

    const int lr = t >> 4, lc = t & 15;
#pragma unroll
    for (int p = 0; p < 4; ++p) {
        const int r = p * 16 + lr;
        const int c = lc * 4;
        const size_t gi = (size_t)(krel + r) * dout_ + col0 + c;
        float v0, v1, v2, v3;
        if (f32) {
            float4 v = *(const float4*)((const float*)src + gi);
            v0 = v.x; v1 = v.y; v2 = v.z; v3 = v.w;
        } else {
            ushort4 u = *(const ushort4*)((const unsigned short*)src + gi);
            __hip_bfloat16 h0, h1, h2, h3;
            *(unsigned short*)&h0 = u.x; *(unsigned short*)&h1 = u.y;
            *(unsigned short*)&h2 = u.z; *(unsigned short*)&h3 = u.w;
            v0 = __bfloat162float(h0); v1 = __bfloat162float(h1);
            v2 = __bfloat162float(h2); v3 = __bfloat162float(h3);
        }
        T[r][c] = sg * v0; T[r][c + 1] = sg * v1;
        T[r][c + 2] = sg * v2; T[r][c + 3] = sg * v3;
    }
    __syncthreads();
#pragma unroll
    for (int q = 0; q < 4; ++q) {
        const int n = q * 16 + lr;
        const int k8 = lc;
        ushort4 u;
        u.x = f2bf(T[k8 * 4 + 0][n]); u.y = f2bf(T[k8 * 4 + 1][n]);
        u.z = f2bf(T[k8 * 4 + 2][n]); u.w = f2bf(T[k8 * 4 + 3][n]);
        *(ushort4*)((unsigned short*)dst + (size_t)(n0 + n) * KT + k0 + k8 * 4) = u;
    }
}

// ---------------------------------------------------------------------------
// GEMM: C = tanh(A @ Bt^T + bias). MT x NT tile, BK=64, 4 waves (2x2),
// 16x16x32 bf16 MFMA, XOR-swizzled LDS (slot = q ^ (row&7); conflicts
// measured 0 in R3). GX n-tiles; GX>=8 -> XCD-aware 1-D mapping.
// MODE 1: scatter row r=t*64+b -> out[b][t][c], dtype per flag.
// ---------------------------------------------------------------------------
template<int MT, int NT, int GX, int MODE>
__global__ __launch_bounds__(256)
void gemm_bias_tanh(const __hip_bfloat16* __restrict__ A,
                    const __hip_bfloat16* __restrict__ Bt,
                    const float* __restrict__ bias,
                    void* __restrict__ Cv, const int* __restrict__ flag,
                    int N, int K)
{
    constexpr int AI = MT / 32;
    constexpr int BJ = NT / 32;
    __shared__ __align__(16) __hip_bfloat16 As[MT * 64];
    __shared__ __align__(16) __hip_bfloat16 Bs[NT * 64];

    const int tid = threadIdx.x, lane = tid & 63, w = tid >> 6;
    const int wx = w & 1, wy = w >> 1;

    int nt, mt;
    const int bid = blockIdx.x;
    if constexpr (GX >= 8) {
        constexpr int XG = GX >> 3;
        const int xcd = bid & 7, r = bid >> 3;
        nt = xcd * XG + (r % XG);
        mt = r / XG;
    } else {
        nt = bid % GX;
        mt = bid / GX;
    }
    const int m0 = mt * MT;
    const int n0 = nt * NT;

    // staging: 16B chunk at (row, slot s) holds global k-quad q = s ^ (row&7)
    const int sl = lane & 7, lr8 = lane >> 3;
    const __hip_bfloat16* gA[AI];
    const __hip_bfloat16* gB[BJ];
#pragma unroll
    for (int p = 0; p < AI; ++p) {
        const int row = w * (MT / 4) + p * 8 + lr8;
        gA[p] = A + (size_t)(m0 + row) * K + (sl ^ (row & 7)) * 8;
    }
#pragma unroll
    for (int p = 0; p < BJ; ++p) {
        const int row = w * (NT / 4) + p * 8 + lr8;
        gB[p] = Bt + (size_t)(n0 + row) * K + (sl ^ (row & 7)) * 8;
    }
    AS3 char* lA = (AS3 char*)As + w * (MT * 32);
    AS3 char* lB = (AS3 char*)Bs + w * (NT * 32);

    // fragment reads: row R, k-quad KQ = ks*4+fq, slot = KQ ^ (R&7)
    const int fr = lane & 15, fq = lane >> 4;
    const int swz = (fq ^ (fr & 7)) * 8;
    const int arow = wy * (MT / 2) + fr;
    const int brow = wx * (NT / 2) + fr;

    f32x4 acc[AI][BJ];
#pragma unroll
    for (int i = 0; i < AI; ++i)
#pragma unroll
        for (int j = 0; j < BJ; ++j)
            acc[i][j] = (f32x4){0.f, 0.f, 0.f, 0.f};

    const int NKT = K >> 6;
    for (int kt = 0; kt < NKT; ++kt) {
        const int kk = kt << 6;
#pragma unroll
        for (int p = 0; p < AI; ++p) gload_lds16(gA[p] + kk, lA + p * 1024);
#pragma unroll
        for (int p = 0; p < BJ; ++p) gload_lds16(gB[p] + kk, lB + p * 1024);
        __syncthreads();
#pragma unroll
        for (int ks = 0; ks < 2; ++ks) {
            const int so = swz ^ (ks << 5);
            bf16x8 af[AI], bv[BJ];
#pragma unroll
            for (int i = 0; i < AI; ++i)
                af[i] = *(const bf16x8*)(As + (arow + i * 16) * 64 + so);
#pragma unroll
            for (int j = 0; j < BJ; ++j)
                bv[j] = *(const bf16x8*)(Bs + (brow + j * 16) * 64 + so);
#pragma unroll
            for (int i = 0; i < AI; ++i)
#pragma unroll
                for (int j = 0; j < BJ; ++j)
                    acc[i][j] = __builtin_amdgcn_mfma_f32_16x16x32_bf16(af[i], bv[j], acc[i][j], 0, 0, 0);
        }
        __syncthreads();
    }

    // epilogue: C/D layout col = lane&15, row = (lane>>4)*4 + reg
    const int col_l = lane & 15;
    const int rq    = lane >> 4;
    const int f32   = (MODE == 1) ? *flag : 0;
    float bvv[BJ];
#pragma unroll
    for (int j = 0; j < BJ; ++j)
        bvv[j] = bias[n0 + wx * (NT / 2) + j * 16 + col_l];

#pragma unroll
    for (int i = 0; i < AI; ++i) {
#pragma unroll
        for (int j = 0; j < BJ; ++j) {
            const int gc = n0 + wx * (NT / 2) + j * 16 + col_l;
#pragma unroll
            for (int r = 0; r < 4; ++r) {
                const int gr = m0 + wy * (MT / 2) + i * 16 + rq * 4 + r;
                const float v = fast_tanh(acc[i][j][r] + bvv[j]);
                if (MODE == 0) {
                    ((__hip_bfloat16*)Cv)[(size_t)gr * (size_t)N + gc] = __float2bfloat16(v);
                } else {
                    const size_t idx = (size_t)(gr & 63) * 32768 + (size_t)(gr >> 6) * 256 + (size_t)gc;
                    if (f32) ((float*)Cv)[idx] = v;
                    else     ((__hip_bfloat16*)Cv)[idx] = __float2bfloat16(v);
                }
            }
        }
    }
}

// ---------------------------------------------------------------------------
// ws: [0,16M) Z (8192x1024 bf16; reused as H1), [16M,48M) H0 (8192x2048),
// [48M) WT0 4M, [52M) WT1 4M, [56M) WT2 0.5M, [56M+512K) bias f32, [57M) flag.
// ---------------------------------------------------------------------------
extern "C" void kernel_launch(void* const* d_in, const int* in_sizes, int n_in,
                              void* d_out, int out_size, void* d_ws, size_t ws_size,
                              hipStream_t stream)
{
    (void)in_sizes; (void)n_in; (void)out_size; (void)ws_size;
    char* ws = (char*)d_ws;
    __hip_bfloat16* Z    = (__hip_bfloat16*)(ws);
    __hip_bfloat16* H0   = (__hip_bfloat16*)(ws + (16u << 20));
    __hip_bfloat16* WT0  = (__hip_bfloat16*)(ws + (48u << 20));
    __hip_bfloat16* WT1  = (__hip_bfloat16*)(ws + (52u << 20));
    __hip_bfloat16* WT2  = (__hip_bfloat16*)(ws + (56u << 20));
    float*          bias = (float*)        (ws + (56u << 20) + (512u << 10));
    int*            flag = (int*)          (ws + (57u << 20));

    setup_all<<<1229, 256, 0, stream>>>(d_in[0], d_in[1], d_in[2],
                                        d_in[3], d_in[4], d_in[7], d_in[8], d_in[11], d_in[12],
                                        d_in[5], d_in[6], d_in[9], d_in[10], d_in[13],
                                        Z, WT0, WT1, WT2, bias, flag, (char*)d_out);

    // G0: Z (8192x1024) @ WT0^T -> H0 (8192x2048). 128x128, 1024 blocks, GX=16.
    gemm_bias_tanh<128, 128, 16, 0><<<1024, 256, 0, stream>>>(Z, WT0, bias, H0, flag, 2048, 1024);
    // G1: H0 @ WT1^T -> H1=Z (8192x1024). 128x128, 512 blocks, GX=8.
    gemm_bias_tanh<128, 128, 8, 0><<<512, 256, 0, stream>>>(H0, WT1, bias + 2048, Z, flag, 1024, 2048);
    // G2: H1 @ WT2^T -> out[b][t][c] (N=256). 64x64, 512 blocks (2/CU), GX=4.
    gemm_bias_tanh<64, 64, 4, 1><<<512, 256, 0, stream>>>(Z, WT2, bias + 3072, d_out, flag, 256, 1024);
}

// Round 7
// 206.589 us; speedup vs baseline: 1.3316x; 1.0096x over previous
//
#include <hip/hip_runtime.h>
#include <hip/hip_bf16.h>
#include <stdint.h>

#define AS1 __attribute__((address_space(1)))
#define AS3 __attribute__((address_space(3)))

typedef __bf16 bf16x8 __attribute__((ext_vector_type(8)));
typedef float f32x4 __attribute__((ext_vector_type(4)));

__device__ __forceinline__ float fast_tanh(float x) {
    float e = __expf(2.0f * x);           // inf/0 endpoints give +/-1 exactly, no NaN
    return 1.0f - 2.0f / (e + 1.0f);
}

__device__ __forceinline__ float ldin(const void* p, int idx, int f32) {
    return f32 ? ((const float*)p)[idx]
               : __bfloat162float(((const __hip_bfloat16*)p)[idx]);
}

__device__ __forceinline__ unsigned short f2bf(float v) {
    __hip_bfloat16 h = __float2bfloat16(v);
    return *(unsigned short*)&h;
}

__device__ __forceinline__ void gload_lds16(const __hip_bfloat16* g, AS3 char* l) {
    __builtin_amdgcn_global_load_lds((AS1 void*)g, (AS3 void*)l, 16, 0, 0);
}

// ---------------------------------------------------------------------------
// 64x64 weight-transpose tile (coalesced both sides via LDS, +1-pad fp32).
// WcT[n][k] = n<dout ? [Wr | -Wi] : [Wi | Wr]  (cols: k<din | k>=din).
// smem must hold 64*65*4 = 16640 B.
// ---------------------------------------------------------------------------
__device__ __forceinline__ void wt_tile(const void* Wr, const void* Wi,
                                        int din, int dout_, int KT, int nt, int kt,
                                        __hip_bfloat16* dst, int f32, char* smem)
{
    float (*T)[65] = (float(*)[65])smem;
    const int t = threadIdx.x;
    const int n0 = nt * 64, k0 = kt * 64;
    const void* src; float sg; int col0, krel;
    if (n0 < dout_) {
        col0 = n0;
        if (k0 < din) { src = Wr; sg =  1.f; krel = k0; }
        else          { src = Wi; sg = -1.f; krel = k0 - din; }
    } else {
        col0 = n0 - dout_;
        if (k0 < din) { src = Wi; sg =  1.f; krel = k0; }
        else          { src = Wr; sg =  1.f; krel = k0 - din; }
    }
    const int lr = t >> 4, lc = t & 15;
#pragma unroll
    for (int p = 0; p < 4; ++p) {
        const int r = p * 16 + lr;
        const int c = lc * 4;
        const size_t gi = (size_t)(krel + r) * dout_ + col0 + c;
        float v0, v1, v2, v3;
        if (f32) {
            float4 v = *(const float4*)((const float*)src + gi);
            v0 = v.x; v1 = v.y; v2 = v.z; v3 = v.w;
        } else {
            ushort4 u = *(const ushort4*)((const unsigned short*)src + gi);
            __hip_bfloat16 h0, h1, h2, h3;
            *(unsigned short*)&h0 = u.x; *(unsigned short*)&h1 = u.y;
            *(unsigned short*)&h2 = u.z; *(unsigned short*)&h3 = u.w;
            v0 = __bfloat162float(h0); v1 = __bfloat162float(h1);
            v2 = __bfloat162float(h2); v3 = __bfloat162float(h3);
        }
        T[r][c] = sg * v0; T[r][c + 1] = sg * v1;
        T[r][c + 2] = sg * v2; T[r][c + 3] = sg * v3;
    }
    __syncthreads();
#pragma unroll
    for (int q = 0; q < 4; ++q) {
        const int n = q * 16 + lr;
        const int k8 = lc;
        ushort4 u;
        u.x = f2bf(T[k8 * 4 + 0][n]); u.y = f2bf(T[k8 * 4 + 1][n]);
        u.z = f2bf(T[k8 * 4 + 2][n]); u.w = f2bf(T[k8 * 4 + 3][n]);
        *(ushort4*)((unsigned short*)dst + (size_t)(n0 + n) * KT + k0 + k8 * 4) = u;
    }
}

// ---------------------------------------------------------------------------
// Setup1: 653 blocks. [0,128) hopf | [128,640) WT0 transpose | [640,653) bias
// (block 640 publishes the dtype flag). Per-block inline dtype probe on z's
// first 512 u16 words (fp32 data ~22% huge bf16 exponents; bf16 none).
// ---------------------------------------------------------------------------
__global__ __launch_bounds__(256)
void setup1(const void* __restrict__ z, const void* __restrict__ omega,
            const void* __restrict__ bc,
            const void* __restrict__ W0r, const void* __restrict__ W0i,
            const void* __restrict__ b0r, const void* __restrict__ b0i,
            const void* __restrict__ b1r, const void* __restrict__ b1i,
            const void* __restrict__ b2r,
            __hip_bfloat16* __restrict__ Z, __hip_bfloat16* __restrict__ WT0,
            float* __restrict__ biasOut, int* __restrict__ flagOut,
            char* __restrict__ dout)
{
    __shared__ __align__(16) char smem[16640];
    __shared__ int sflag;
    const int t   = threadIdx.x;
    const int bid = blockIdx.x;

    if (t == 0) sflag = 0;
    __syncthreads();
    {
        const unsigned short* zz = (const unsigned short*)z;
        const int c = ((((zz[t] >> 7) & 0xFF) >= 0xC8) ? 1 : 0)
                    + ((((zz[t + 256] >> 7) & 0xFF) >= 0xC8) ? 1 : 0);
        if (c) atomicAdd(&sflag, c);
    }
    __syncthreads();
    const int f32 = (sflag > 8) ? 1 : 0;

    if (bid < 128) {
        // Hopf trajectory: one thread per (b,i), 128 fp32 Euler steps
        const int tid = bid * 256 + t;
        const int b = tid >> 9;
        const int i = tid & 511;
        float x = ldin(z, b * 1024 + i, f32);
        float y = ldin(z, b * 1024 + 512 + i, f32);
        const float om = ldin(omega, b, f32);
        const float bb = ldin(bc, b * 512 + i, f32);
        const float w  = om * (float)(i + 1);
        __hip_bfloat16* zt = Z + b * 1024 + i;
        for (int s = 0; s < 128; ++s) {
            const float r2 = x * x + y * y;
            const float f  = bb - r2;
            const float dx = f * x - w * y;
            const float dy = f * y + w * x;
            x += 0.001f * dx;
            y += 0.001f * dy;
            zt[s * 65536]       = __float2bfloat16(x);
            zt[s * 65536 + 512] = __float2bfloat16(y);
            if (s == 0) {
                if (f32) {
                    float* o = (float*)(dout + (size_t)2097152 * 4);
                    o[b * 1024 + i] = x; o[b * 1024 + 512 + i] = y;
                } else {
                    __hip_bfloat16* o = (__hip_bfloat16*)(dout + (size_t)2097152 * 2);
                    o[b * 1024 + i] = __float2bfloat16(x);
                    o[b * 1024 + 512 + i] = __float2bfloat16(y);
                }
            }
        }
        return;
    }

    if (bid >= 640) {
        if (bid == 640 && t == 0) *flagOut = f32;
        const int idx = (bid - 640) * 256 + t;   // [0,3328)
        float v;
        if      (idx < 1024) v = ldin(b0r, idx, f32);
        else if (idx < 2048) v = ldin(b0i, idx - 1024, f32);
        else if (idx < 2560) v = ldin(b1r, idx - 2048, f32);
        else if (idx < 3072) v = ldin(b1i, idx - 2560, f32);
        else                 v = ldin(b2r, idx - 3072, f32);
        biasOut[idx] = v;
        return;
    }

    // WT0: 2048 x 1024, tiles: nt = u>>4 (32), kt = u&15 (16)
    const int u = bid - 128;
    wt_tile(W0r, W0i, 512, 1024, 1024, u >> 4, u & 15, WT0, f32, smem);
}

// ---------------------------------------------------------------------------
// GEMM core: C = tanh(A @ Bt^T + bias). MT x NT tile, BK=64, 4 waves (2x2),
// 16x16x32 bf16 MFMA, XOR-swizzled LDS (slot = q ^ (row&7); conflicts
// measured 0 in R3). GX n-tiles; GX>=8 -> XCD-aware mapping.
// MODE 1: scatter row r=t*64+b -> out[b][t][c], dtype per f32.
// ---------------------------------------------------------------------------
template<int MT, int NT, int GX, int MODE>
__device__ __forceinline__ void gemm_core(int bid,
                                          const __hip_bfloat16* __restrict__ A,
                                          const __hip_bfloat16* __restrict__ Bt,
                                          const float* __restrict__ bias,
                                          void* __restrict__ Cv, int f32,
                                          int N, int K, char* smem)
{
    constexpr int AI = MT / 32;
    constexpr int BJ = NT / 32;
    __hip_bfloat16* As = (__hip_bfloat16*)smem;
    __hip_bfloat16* Bs = (__hip_bfloat16*)(smem + MT * 128);

    const int tid = threadIdx.x, lane = tid & 63, w = tid >> 6;
    const int wx = w & 1, wy = w >> 1;

    int nt, mt;
    if constexpr (GX >= 8) {
        constexpr int XG = GX >> 3;
        const int xcd = bid & 7, r = bid >> 3;
        nt = xcd * XG + (r % XG);
        mt = r / XG;
    } else {
        nt = bid % GX;
        mt = bid / GX;
    }
    const int m0 = mt * MT;
    const int n0 = nt * NT;

    // staging: 16B chunk at (row, slot s) holds global k-quad q = s ^ (row&7)
    const int sl = lane & 7, lr8 = lane >> 3;
    const __hip_bfloat16* gA[AI];
    const __hip_bfloat16* gB[BJ];
#pragma unroll
    for (int p = 0; p < AI; ++p) {
        const int row = w * (MT / 4) + p * 8 + lr8;
        gA[p] = A + (size_t)(m0 + row) * K + (sl ^ (row & 7)) * 8;
    }
#pragma unroll
    for (int p = 0; p < BJ; ++p) {
        const int row = w * (NT / 4) + p * 8 + lr8;
        gB[p] = Bt + (size_t)(n0 + row) * K + (sl ^ (row & 7)) * 8;
    }
    AS3 char* lA = (AS3 char*)As + w * (MT * 32);
    AS3 char* lB = (AS3 char*)Bs + w * (NT * 32);

    // fragment reads: row R, k-quad KQ = ks*4+fq, slot = KQ ^ (R&7)
    const int fr = lane & 15, fq = lane >> 4;
    const int swz = (fq ^ (fr & 7)) * 8;
    const int arow = wy * (MT / 2) + fr;
    const int brow = wx * (NT / 2) + fr;

    f32x4 acc[AI][BJ];
#pragma unroll
    for (int i = 0; i < AI; ++i)
#pragma unroll
        for (int j = 0; j < BJ; ++j)
            acc[i][j] = (f32x4){0.f, 0.f, 0.f, 0.f};

    const int NKT = K >> 6;
    for (int kt = 0; kt < NKT; ++kt) {
        const int kk = kt << 6;
#pragma unroll
        for (int p = 0; p < AI; ++p) gload_lds16(gA[p] + kk, lA + p * 1024);
#pragma unroll
        for (int p = 0; p < BJ; ++p) gload_lds16(gB[p] + kk, lB + p * 1024);
        __syncthreads();
#pragma unroll
        for (int ks = 0; ks < 2; ++ks) {
            const int so = swz ^ (ks << 5);
            bf16x8 af[AI], bv[BJ];
#pragma unroll
            for (int i = 0; i < AI; ++i)
                af[i] = *(const bf16x8*)(As + (arow + i * 16) * 64 + so);
#pragma unroll
            for (int j = 0; j < BJ; ++j)
                bv[j] = *(const bf16x8*)(Bs + (brow + j * 16) * 64 + so);
#pragma unroll
            for (int i = 0; i < AI; ++i)
#pragma unroll
                for (int j = 0; j < BJ; ++j)
                    acc[i][j] = __builtin_amdgcn_mfma_f32_16x16x32_bf16(af[i], bv[j], acc[i][j], 0, 0, 0);
        }
        __syncthreads();
    }

    // epilogue: C/D layout col = lane&15, row = (lane>>4)*4 + reg
    const int col_l = lane & 15;
    const int rq    = lane >> 4;
    float bvv[BJ];
#pragma unroll
    for (int j = 0; j < BJ; ++j)
        bvv[j] = bias[n0 + wx * (NT / 2) + j * 16 + col_l];

#pragma unroll
    for (int i = 0; i < AI; ++i) {
#pragma unroll
        for (int j = 0; j < BJ; ++j) {
            const int gc = n0 + wx * (NT / 2) + j * 16 + col_l;
#pragma unroll
            for (int r = 0; r < 4; ++r) {
                const int gr = m0 + wy * (MT / 2) + i * 16 + rq * 4 + r;
                const float v = fast_tanh(acc[i][j][r] + bvv[j]);
                if (MODE == 0) {
                    ((__hip_bfloat16*)Cv)[(size_t)gr * (size_t)N + gc] = __float2bfloat16(v);
                } else {
                    const size_t idx = (size_t)(gr & 63) * 32768 + (size_t)(gr >> 6) * 256 + (size_t)gc;
                    if (f32) ((float*)Cv)[idx] = v;
                    else     ((__hip_bfloat16*)Cv)[idx] = __float2bfloat16(v);
                }
            }
        }
    }
}

// ---------------------------------------------------------------------------
// D2: blocks [0,1024) = G0 tiles (128x128, GX=16 XCD); [1024,1536) = WT1
// transpose; [1536,1600) = WT2 transpose (run in G0's ramp/tail slack; WT1/2
// only needed by later dispatches).
// ---------------------------------------------------------------------------
__global__ __launch_bounds__(256)
void gemm0_wt(const __hip_bfloat16* __restrict__ A,
              const __hip_bfloat16* __restrict__ Bt,
              const float* __restrict__ bias, void* __restrict__ Cv,
              const void* __restrict__ W1r, const void* __restrict__ W1i,
              const void* __restrict__ W2r, const void* __restrict__ W2i,
              __hip_bfloat16* __restrict__ WT1, __hip_bfloat16* __restrict__ WT2,
              const int* __restrict__ flag)
{
    __shared__ __align__(16) char smem[32768];
    const int bid = blockIdx.x;
    if (bid < 1024) {
        gemm_core<128, 128, 16, 0>(bid, A, Bt, bias, Cv, 0, 2048, 1024, smem);
    } else if (bid < 1536) {
        const int u = bid - 1024;   // WT1: 1024 x 2048, nt = u>>5 (16), kt = u&31 (32)
        wt_tile(W1r, W1i, 1024, 512, 2048, u >> 5, u & 31, WT1, *flag, smem);
    } else {
        const int u = bid - 1536;   // WT2: 256 x 1024, nt = u>>4 (4), kt = u&15 (16)
        wt_tile(W2r, W2i, 512, 256, 1024, u >> 4, u & 15, WT2, *flag, smem);
    }
}

template<int MT, int NT, int GX, int MODE>
__global__ __launch_bounds__(256)
void gemm_k(const __hip_bfloat16* __restrict__ A, const __hip_bfloat16* __restrict__ Bt,
            const float* __restrict__ bias, void* __restrict__ Cv,
            const int* __restrict__ flag, int N, int K)
{
    __shared__ __align__(16) char smem[(MT + NT) * 128];
    const int f32 = (MODE == 1) ? *flag : 0;
    gemm_core<MT, NT, GX, MODE>(blockIdx.x, A, Bt, bias, Cv, f32, N, K, smem);
}

// ---------------------------------------------------------------------------
// ws: [0,16M) Z (8192x1024 bf16; reused as H1), [16M,48M) H0 (8192x2048),
// [48M) WT0 4M, [52M) WT1 4M, [56M) WT2 0.5M, [56M+512K) bias f32, [57M) flag.
// ---------------------------------------------------------------------------
extern "C" void kernel_launch(void* const* d_in, const int* in_sizes, int n_in,
                              void* d_out, int out_size, void* d_ws, size_t ws_size,
                              hipStream_t stream)
{
    (void)in_sizes; (void)n_in; (void)out_size; (void)ws_size;
    char* ws = (char*)d_ws;
    __hip_bfloat16* Z    = (__hip_bfloat16*)(ws);
    __hip_bfloat16* H0   = (__hip_bfloat16*)(ws + (16u << 20));
    __hip_bfloat16* WT0  = (__hip_bfloat16*)(ws + (48u << 20));
    __hip_bfloat16* WT1  = (__hip_bfloat16*)(ws + (52u << 20));
    __hip_bfloat16* WT2  = (__hip_bfloat16*)(ws + (56u << 20));
    float*          bias = (float*)        (ws + (56u << 20) + (512u << 10));
    int*            flag = (int*)          (ws + (57u << 20));

    // D1: hopf + WT0 + bias (+flag publish)
    setup1<<<653, 256, 0, stream>>>(d_in[0], d_in[1], d_in[2], d_in[3], d_in[4],
                                    d_in[5], d_in[6], d_in[9], d_in[10], d_in[13],
                                    Z, WT0, bias, flag, (char*)d_out);

    // D2: G0 (Z @ WT0^T -> H0, 8192x2048) + WT1/WT2 transposes in slack
    gemm0_wt<<<1600, 256, 0, stream>>>(Z, WT0, bias, H0,
                                       d_in[7], d_in[8], d_in[11], d_in[12],
                                       WT1, WT2, flag);

    // D3: G1 = H0 @ WT1^T -> H1=Z (8192x1024). 128x64 tiles, 1024 blocks, GX=16.
    gemm_k<128, 64, 16, 0><<<1024, 256, 0, stream>>>(H0, WT1, bias + 2048, Z, flag, 1024, 2048);

    // D4: G2 = H1 @ WT2^T -> out[b][t][c] (N=256). 64x64, 512 blocks, GX=4.
    gemm_k<64, 64, 4, 1><<<512, 256, 0, stream>>>(Z, WT2, bias + 3072, d_out, flag, 256, 1024);
}